// Round 1
// baseline (25.250 us; speedup 1.0000x reference)
//
#include <hip/hip_runtime.h>
#include <math.h>

#define NB 256     // batch
#define NN 2048    // nodes
#define NE 128     // emb
#define NORMC 0.08838834764831845f  // 1/sqrt(128)

__device__ __forceinline__ float wave_red_sum(float v) {
  #pragma unroll
  for (int o = 32; o; o >>= 1) v += __shfl_down(v, o, 64);
  return v;
}

__global__ __launch_bounds__(256)
void age_kernel(const float* __restrict__ nodef,   // [B,N,3]
                const float* __restrict__ state,   // [B,4]
                const float* __restrict__ W_node,  // [3,128]
                const float* __restrict__ b_node,  // [128]
                const float* __restrict__ W_depot, // [2,128]
                const float* __restrict__ b_depot, // [128]
                const float* __restrict__ W_state, // [4,128]
                const float* __restrict__ b_state, // [128]
                const float* __restrict__ w_q,     // [384,128]
                const float* __restrict__ w_k,     // [256,128]
                const float* __restrict__ w_v,     // [256,128]
                const int*   __restrict__ curr_id, // [B]
                const int*   __restrict__ next_id, // [B]
                const void*  __restrict__ maskp,   // [B,N] bool (width detected)
                float* __restrict__ out)           // [B,128]
{
  const int b = blockIdx.x;
  const int t = threadIdx.x;

  __shared__ float nf3[NN * 3];      // 24 KB raw node feats for this batch
  __shared__ float compat[NN];       // 8 KB masked logits
  // tbl rows: 0-2 Ak, 3-5 Av, 6-7 Dk, 8-9 Dv, 10 ck, 11 cv, 12 dk, 13 dv
  __shared__ float tbl[14 * NE];     // 7 KB fused weight table
  __shared__ float curr[NE], nxt[NE], stv[NE], qv[NE], kc[NE], vc[NE];
  __shared__ float red[24];
  __shared__ float scal[8];
  __shared__ float se0;
  __shared__ int   sflag;

  // ---- detect mask element width: bit0 -> 1-byte, bit1 -> 4-byte, none -> 8-byte
  if (t == 0) sflag = 0;
  __syncthreads();
  {
    const unsigned char* mb = (const unsigned char*)maskp;
    int f = 0;
    const int base = t * 16;        // scans first 4096 bytes (buffer >= 512 KB)
    #pragma unroll
    for (int i = 0; i < 16; ++i) {
      int idx = base + i;
      unsigned char v = mb[idx];
      if (v) {
        if (idx & 3) f |= 1;        // nonzero at sub-word byte -> byte storage
        else if (idx & 7) f |= 2;   // nonzero at odd 32-bit word -> int32 storage
      }
    }
    if (f) atomicOr(&sflag, f);
  }

  // ---- stage node feats to LDS (coalesced)
  {
    const float* nb = nodef + (size_t)b * (NN * 3);
    for (int i = t; i < NN * 3; i += 256) nf3[i] = nb[i];
  }

  // ---- fused weight table: threads 0-127 -> k side, 128-255 -> v side
  {
    const int e = t & 127;
    const float* w2 = ((t < 128) ? w_k : w_v) + 128 * NE + e;  // second-half rows, col e
    float a0 = 0, a1 = 0, a2 = 0, d0 = 0, d1 = 0, cb = 0, db = 0;
    #pragma unroll 8
    for (int j = 0; j < 128; ++j) {
      float w = w2[j * NE];
      a0 += W_node[j]       * w;
      a1 += W_node[128 + j] * w;
      a2 += W_node[256 + j] * w;
      d0 += W_depot[j]      * w;
      d1 += W_depot[128 + j]* w;
      cb += b_node[j]       * w;
      db += b_depot[j]      * w;
    }
    if (t < 128) {
      tbl[0*NE+e]=a0; tbl[1*NE+e]=a1; tbl[2*NE+e]=a2;
      tbl[6*NE+e]=d0; tbl[7*NE+e]=d1;
      tbl[10*NE+e]=cb; tbl[12*NE+e]=db;
    } else {
      tbl[3*NE+e]=a0; tbl[4*NE+e]=a1; tbl[5*NE+e]=a2;
      tbl[8*NE+e]=d0; tbl[9*NE+e]=d1;
      tbl[11*NE+e]=cb; tbl[13*NE+e]=db;
    }
  }
  __syncthreads();

  // ---- curr / next / state embeddings
  if (t < 128) {
    const int cid = curr_id[b];
    float v;
    if (cid == 0)
      v = nf3[0]*W_depot[t] + nf3[1]*W_depot[128+t] + b_depot[t];
    else
      v = nf3[3*cid]*W_node[t] + nf3[3*cid+1]*W_node[128+t]
        + nf3[3*cid+2]*W_node[256+t] + b_node[t];
    curr[t] = v;
    float s = b_state[t];
    #pragma unroll
    for (int r = 0; r < 4; ++r) s += state[b*4+r] * W_state[r*NE+t];
    stv[t] = s;
  } else {
    const int e = t - 128;
    const int nid = next_id[b];
    float v;
    if (nid == 0)
      v = nf3[0]*W_depot[e] + nf3[1]*W_depot[128+e] + b_depot[e];
    else
      v = nf3[3*nid]*W_node[e] + nf3[3*nid+1]*W_node[128+e]
        + nf3[3*nid+2]*W_node[256+e] + b_node[e];
    nxt[e] = v;
  }
  __syncthreads();

  // ---- q (384-dot) on threads 0-127; kc & vc (128-dots) on threads 128-255
  if (t < 128) {
    float acc = 0;
    #pragma unroll 8
    for (int j = 0; j < 128; ++j) acc += curr[j] * w_q[j*NE + t];
    #pragma unroll 8
    for (int j = 0; j < 128; ++j) acc += nxt[j]  * w_q[(128+j)*NE + t];
    #pragma unroll 8
    for (int j = 0; j < 128; ++j) acc += stv[j]  * w_q[(256+j)*NE + t];
    qv[t] = acc;
  } else {
    const int e = t - 128;
    float a1 = 0, a2 = 0;
    #pragma unroll 8
    for (int j = 0; j < 128; ++j) {
      float cj = curr[j];
      a1 += cj * w_k[j*NE + e];
      a2 += cj * w_v[j*NE + e];
    }
    kc[e] = a1; vc[e] = a2;
  }
  __syncthreads();

  // ---- 8 dots of q with {kc, ck, dk, Ak0..2, Dk0..1}; 32 lanes each
  {
    const int g = t >> 5, l = t & 31;
    const float* vg =
      (g == 0) ? kc :
      (g == 1) ? (tbl + 10*NE) :
      (g == 2) ? (tbl + 12*NE) :
      (g <= 5) ? (tbl + (g-3)*NE) :
                 (tbl + (6 + (g-6))*NE);
    float p = 0;
    #pragma unroll
    for (int e = l; e < 128; e += 32) p += qv[e] * vg[e];
    #pragma unroll
    for (int o = 16; o; o >>= 1) p += __shfl_down(p, o, 32);
    if (l == 0) scal[g] = p;
  }
  __syncthreads();

  const float qkc = scal[0], qck = scal[1], qdk = scal[2];
  const float gk0 = scal[3], gk1 = scal[4], gk2 = scal[5];
  const float gdk0 = scal[6], gdk1 = scal[7];
  const int mflag = sflag;
  const unsigned char* m8  = (const unsigned char*)maskp;
  const int*           m32 = (const int*)maskp;
  const long long*     m64 = (const long long*)maskp;

  // ---- compat (3-dim dot per node) + masked max
  float lmax = -INFINITY;
  for (int n = t; n < NN; n += 256) {
    float c;
    if (n == 0) c = qkc + qdk + nf3[0]*gdk0 + nf3[1]*gdk1;
    else        c = qkc + qck + nf3[3*n]*gk0 + nf3[3*n+1]*gk1 + nf3[3*n+2]*gk2;
    c *= NORMC;
    const size_t off = (size_t)b * NN + n;
    long long mk;
    if (mflag & 1)      mk = m8[off];
    else if (mflag & 2) mk = m32[off];
    else                mk = m64[off];
    c = mk ? c : -INFINITY;
    compat[n] = c;
    lmax = fmaxf(lmax, c);
  }
  #pragma unroll
  for (int o = 32; o; o >>= 1) lmax = fmaxf(lmax, __shfl_down(lmax, o, 64));
  if ((t & 63) == 0) red[t >> 6] = lmax;
  __syncthreads();
  const float m = fmaxf(fmaxf(red[0], red[1]), fmaxf(red[2], red[3]));

  // ---- exp + sums: denom and 3-component weighted feature sum (n>=1)
  float le = 0, s0 = 0, s1 = 0, s2 = 0;
  for (int n = t; n < NN; n += 256) {
    float e = __expf(compat[n] - m);
    le += e;
    if (n == 0) se0 = e;   // only thread 0 hits n==0
    else { s0 += e*nf3[3*n]; s1 += e*nf3[3*n+1]; s2 += e*nf3[3*n+2]; }
  }
  le = wave_red_sum(le);
  s0 = wave_red_sum(s0);
  s1 = wave_red_sum(s1);
  s2 = wave_red_sum(s2);
  {
    const int w = t >> 6;
    if ((t & 63) == 0) { red[4+w]=le; red[8+w]=s0; red[12+w]=s1; red[16+w]=s2; }
  }
  __syncthreads();
  const float L  = red[4]  + red[5]  + red[6]  + red[7];
  const float S0 = red[8]  + red[9]  + red[10] + red[11];
  const float S1 = red[12] + red[13] + red[14] + red[15];
  const float S2 = red[16] + red[17] + red[18] + red[19];

  // ---- epilogue: h = vc + (1-a0)*cv + (S@Av)/L + a0*(x0@Dv + dv)
  if (t < 128) {
    const float a0 = se0 / L;
    const float hv = vc[t]
      + (1.0f - a0) * tbl[11*NE + t]
      + (S0*tbl[3*NE+t] + S1*tbl[4*NE+t] + S2*tbl[5*NE+t]) / L
      + a0 * (nf3[0]*tbl[8*NE+t] + nf3[1]*tbl[9*NE+t] + tbl[13*NE+t]);
    out[(size_t)b*NE + t] = hv;
  }
}

extern "C" void kernel_launch(void* const* d_in, const int* in_sizes, int n_in,
                              void* d_out, int out_size, void* d_ws, size_t ws_size,
                              hipStream_t stream) {
  (void)in_sizes; (void)n_in; (void)out_size; (void)d_ws; (void)ws_size;
  const float* nodef   = (const float*)d_in[0];
  const float* state   = (const float*)d_in[1];
  const float* W_node  = (const float*)d_in[2];
  const float* b_node  = (const float*)d_in[3];
  const float* W_depot = (const float*)d_in[4];
  const float* b_depot = (const float*)d_in[5];
  const float* W_state = (const float*)d_in[6];
  const float* b_state = (const float*)d_in[7];
  const float* w_q     = (const float*)d_in[8];
  const float* w_k     = (const float*)d_in[9];
  const float* w_v     = (const float*)d_in[10];
  const int*   curr_id = (const int*)d_in[11];
  const int*   next_id = (const int*)d_in[12];
  const void*  maskp   = d_in[13];
  float* out = (float*)d_out;

  hipLaunchKernelGGL(age_kernel, dim3(NB), dim3(256), 0, stream,
                     nodef, state, W_node, b_node, W_depot, b_depot,
                     W_state, b_state, w_q, w_k, w_v,
                     curr_id, next_id, maskp, out);
}

// Round 2
// 19.883 us; speedup vs baseline: 1.2699x; 1.2699x over previous
//
#include <hip/hip_runtime.h>
#include <math.h>

#define NB 256     // batch
#define NN 2048    // nodes
#define NE 128     // emb
#define NT 512     // threads per block
#define NORMC 0.08838834764831845f  // 1/sqrt(128)

__global__ __launch_bounds__(NT)
void age_kernel(const float* __restrict__ nodef,   // [B,N,3]
                const float* __restrict__ state,   // [B,4]
                const float* __restrict__ W_node,  // [3,128]
                const float* __restrict__ b_node,  // [128]
                const float* __restrict__ W_depot, // [2,128]
                const float* __restrict__ b_depot, // [128]
                const float* __restrict__ W_state, // [4,128]
                const float* __restrict__ b_state, // [128]
                const float* __restrict__ w_q,     // [384,128]
                const float* __restrict__ w_k,     // [256,128]
                const float* __restrict__ w_v,     // [256,128]
                const int*   __restrict__ curr_id, // [B]
                const int*   __restrict__ next_id, // [B]
                const void*  __restrict__ maskp,   // [B,N] bool (width detected)
                float* __restrict__ out)           // [B,128]
{
  const int b = blockIdx.x;
  const int t = threadIdx.x;
  const int g = t >> 7;        // 4 groups of 128
  const int e = t & 127;

  __shared__ float nf3[NN * 3];      // 24 KB node feats
  __shared__ float compat[NN];       // 8 KB logits
  // tbl rows: 0-2 Ak, 3-5 Av, 6-7 Dk, 8-9 Dv, 10 ck, 11 cv, 12 dk, 13 dv
  __shared__ float tbl[14 * NE];
  __shared__ float curr[NE], nxt[NE], stv[NE];
  __shared__ float qp[2][NE];
  __shared__ float kc[NE], vc[NE];
  __shared__ float red[40];
  __shared__ float scal[8];
  __shared__ float se0;
  __shared__ int   sflag;

  if (t == 0) sflag = 0;

  // ---- issue node-feat staging loads NOW; ds_write them after phase 2 (T14)
  float4 stg0, stg1, stg2;
  {
    const float4* nb4 = (const float4*)(nodef + (size_t)b * (NN * 3));
    stg0 = nb4[t];
    stg1 = nb4[NT + t];
    stg2 = nb4[2 * NT + t];
  }
  __syncthreads();   // sflag init visible

  // ---- detect mask element width: bit0 -> 1-byte, bit1 -> 4-byte, none -> 8-byte
  {
    const unsigned char* mb = (const unsigned char*)maskp;
    int f = 0;
    const int base = t * 8;         // scans first 4096 bytes
    #pragma unroll
    for (int i = 0; i < 8; ++i) {
      int idx = base + i;
      unsigned char v = mb[idx];
      if (v) {
        if (idx & 3) f |= 1;
        else if (idx & 7) f |= 2;
      }
    }
    if (f) atomicOr(&sflag, f);
  }

  // ---- embeddings (direct global reads; scalar loads for the 3 feats)
  if (g == 0) {
    const int cid = curr_id[b];
    const float* nd = nodef + ((size_t)b * NN + cid) * 3;
    float v;
    if (cid == 0) v = nd[0]*W_depot[e] + nd[1]*W_depot[NE+e] + b_depot[e];
    else          v = nd[0]*W_node[e] + nd[1]*W_node[NE+e] + nd[2]*W_node[2*NE+e] + b_node[e];
    curr[e] = v;
  } else if (g == 1) {
    const int nid = next_id[b];
    const float* nd = nodef + ((size_t)b * NN + nid) * 3;
    float v;
    if (nid == 0) v = nd[0]*W_depot[e] + nd[1]*W_depot[NE+e] + b_depot[e];
    else          v = nd[0]*W_node[e] + nd[1]*W_node[NE+e] + nd[2]*W_node[2*NE+e] + b_node[e];
    nxt[e] = v;
  } else if (g == 2) {
    float s = b_state[e];
    #pragma unroll
    for (int r = 0; r < 4; ++r) s += state[b*4+r] * W_state[r*NE+e];
    stv[e] = s;
  }
  __syncthreads();   // curr/nxt/stv ready; sflag final

  // ---- prefetch mask into registers (consumed 2 syncs later)
  const int mflag = sflag;
  long long mk[4];
  {
    #pragma unroll
    for (int i = 0; i < 4; ++i) {
      const size_t off = (size_t)b * NN + (t + i * NT);
      if (mflag & 1)      mk[i] = ((const unsigned char*)maskp)[off];
      else if (mflag & 2) mk[i] = ((const int*)maskp)[off];
      else                mk[i] = ((const long long*)maskp)[off];
    }
  }

  // ---- phase 2: four 128-thread groups, ~192-256 L2 loads each, deep unroll
  if (g == 0) {                 // q partial: curr full + nxt[0..63]
    float acc = 0;
    #pragma unroll 32
    for (int j = 0; j < NE; ++j) acc += curr[j] * w_q[j*NE + e];
    #pragma unroll 16
    for (int j = 0; j < 64; ++j) acc += nxt[j] * w_q[(NE+j)*NE + e];
    qp[0][e] = acc;
  } else if (g == 1) {          // q partial: nxt[64..127] + stv full
    float acc = 0;
    #pragma unroll 16
    for (int j = 64; j < NE; ++j) acc += nxt[j] * w_q[(NE+j)*NE + e];
    #pragma unroll 32
    for (int j = 0; j < NE; ++j) acc += stv[j] * w_q[(2*NE+j)*NE + e];
    qp[1][e] = acc;
  } else if (g == 2) {          // kc + k-side fused table
    float a0=0,a1=0,a2=0,d0=0,d1=0,cb=0,db=0,ac=0;
    #pragma unroll 16
    for (int j = 0; j < NE; ++j) {
      float w1 = w_k[j*NE + e];
      float w2 = w_k[(NE+j)*NE + e];
      ac += curr[j] * w1;
      a0 += W_node[j]*w2;  a1 += W_node[NE+j]*w2;  a2 += W_node[2*NE+j]*w2;
      d0 += W_depot[j]*w2; d1 += W_depot[NE+j]*w2;
      cb += b_node[j]*w2;  db += b_depot[j]*w2;
    }
    kc[e] = ac;
    tbl[0*NE+e]=a0; tbl[1*NE+e]=a1; tbl[2*NE+e]=a2;
    tbl[6*NE+e]=d0; tbl[7*NE+e]=d1;
    tbl[10*NE+e]=cb; tbl[12*NE+e]=db;
  } else {                      // vc + v-side fused table
    float a0=0,a1=0,a2=0,d0=0,d1=0,cb=0,db=0,ac=0;
    #pragma unroll 16
    for (int j = 0; j < NE; ++j) {
      float w1 = w_v[j*NE + e];
      float w2 = w_v[(NE+j)*NE + e];
      ac += curr[j] * w1;
      a0 += W_node[j]*w2;  a1 += W_node[NE+j]*w2;  a2 += W_node[2*NE+j]*w2;
      d0 += W_depot[j]*w2; d1 += W_depot[NE+j]*w2;
      cb += b_node[j]*w2;  db += b_depot[j]*w2;
    }
    vc[e] = ac;
    tbl[3*NE+e]=a0; tbl[4*NE+e]=a1; tbl[5*NE+e]=a2;
    tbl[8*NE+e]=d0; tbl[9*NE+e]=d1;
    tbl[11*NE+e]=cb; tbl[13*NE+e]=db;
  }

  // ---- deferred staging write (loads issued at kernel start are long done)
  {
    float4* nf4 = (float4*)nf3;
    nf4[t] = stg0; nf4[NT + t] = stg1; nf4[2*NT + t] = stg2;
  }
  __syncthreads();

  // ---- 8 dots of q with {kc, ck, dk, Ak0..2, Dk0..1}; 64 lanes each
  {
    const int gg = t >> 6, l = t & 63;
    const float* vg =
      (gg == 0) ? kc :
      (gg == 1) ? (tbl + 10*NE) :
      (gg == 2) ? (tbl + 12*NE) :
      (gg <= 5) ? (tbl + (gg-3)*NE) :
                  (tbl + gg*NE);      // gg=6,7 -> Dk rows 6,7
    float p = (qp[0][l] + qp[1][l]) * vg[l]
            + (qp[0][64+l] + qp[1][64+l]) * vg[64+l];
    #pragma unroll
    for (int o = 32; o; o >>= 1) p += __shfl_down(p, o, 64);
    if (l == 0) scal[gg] = p;
  }
  __syncthreads();

  const float qkc = scal[0], qck = scal[1], qdk = scal[2];
  const float gk0 = scal[3], gk1 = scal[4], gk2 = scal[5];
  const float gdk0 = scal[6], gdk1 = scal[7];

  // ---- compat + masked max (4 nodes per thread)
  float lmax = -INFINITY;
  #pragma unroll
  for (int i = 0; i < 4; ++i) {
    const int n = t + i * NT;
    float c;
    if (n == 0) c = qkc + qdk + nf3[0]*gdk0 + nf3[1]*gdk1;
    else        c = qkc + qck + nf3[3*n]*gk0 + nf3[3*n+1]*gk1 + nf3[3*n+2]*gk2;
    c *= NORMC;
    c = mk[i] ? c : -INFINITY;
    compat[n] = c;
    lmax = fmaxf(lmax, c);
  }
  #pragma unroll
  for (int o = 32; o; o >>= 1) lmax = fmaxf(lmax, __shfl_down(lmax, o, 64));
  if ((t & 63) == 0) red[t >> 6] = lmax;
  __syncthreads();
  float m = red[0];
  #pragma unroll
  for (int i = 1; i < 8; ++i) m = fmaxf(m, red[i]);

  // ---- exp + sums: denom + 3-component weighted feature sum (n>=1)
  float le = 0, s0 = 0, s1 = 0, s2 = 0;
  #pragma unroll
  for (int i = 0; i < 4; ++i) {
    const int n = t + i * NT;
    float ex = __expf(compat[n] - m);
    le += ex;
    if (n == 0) se0 = ex;     // only thread 0
    else { s0 += ex*nf3[3*n]; s1 += ex*nf3[3*n+1]; s2 += ex*nf3[3*n+2]; }
  }
  #pragma unroll
  for (int o = 32; o; o >>= 1) {
    le += __shfl_down(le, o, 64);
    s0 += __shfl_down(s0, o, 64);
    s1 += __shfl_down(s1, o, 64);
    s2 += __shfl_down(s2, o, 64);
  }
  if ((t & 63) == 0) {
    const int w = t >> 6;
    red[8+w] = le; red[16+w] = s0; red[24+w] = s1; red[32+w] = s2;
  }
  __syncthreads();
  float L = 0, S0 = 0, S1 = 0, S2 = 0;
  #pragma unroll
  for (int i = 0; i < 8; ++i) {
    L += red[8+i]; S0 += red[16+i]; S1 += red[24+i]; S2 += red[32+i];
  }

  // ---- epilogue: h = vc + (1-a0)*cv + (S@Av)/L + a0*(x0@Dv + dv)
  if (t < 128) {
    const float a0 = se0 / L;
    const float hv = vc[t]
      + (1.0f - a0) * tbl[11*NE + t]
      + (S0*tbl[3*NE+t] + S1*tbl[4*NE+t] + S2*tbl[5*NE+t]) / L
      + a0 * (nf3[0]*tbl[8*NE+t] + nf3[1]*tbl[9*NE+t] + tbl[13*NE+t]);
    out[(size_t)b*NE + t] = hv;
  }
}

extern "C" void kernel_launch(void* const* d_in, const int* in_sizes, int n_in,
                              void* d_out, int out_size, void* d_ws, size_t ws_size,
                              hipStream_t stream) {
  (void)in_sizes; (void)n_in; (void)out_size; (void)d_ws; (void)ws_size;
  const float* nodef   = (const float*)d_in[0];
  const float* state   = (const float*)d_in[1];
  const float* W_node  = (const float*)d_in[2];
  const float* b_node  = (const float*)d_in[3];
  const float* W_depot = (const float*)d_in[4];
  const float* b_depot = (const float*)d_in[5];
  const float* W_state = (const float*)d_in[6];
  const float* b_state = (const float*)d_in[7];
  const float* w_q     = (const float*)d_in[8];
  const float* w_k     = (const float*)d_in[9];
  const float* w_v     = (const float*)d_in[10];
  const int*   curr_id = (const int*)d_in[11];
  const int*   next_id = (const int*)d_in[12];
  const void*  maskp   = d_in[13];
  float* out = (float*)d_out;

  hipLaunchKernelGGL(age_kernel, dim3(NB), dim3(NT), 0, stream,
                     nodef, state, W_node, b_node, W_depot, b_depot,
                     W_state, b_state, w_q, w_k, w_v,
                     curr_id, next_id, maskp, out);
}

// Round 3
// 15.051 us; speedup vs baseline: 1.6776x; 1.3211x over previous
//
#include <hip/hip_runtime.h>
#include <math.h>

#define NB 256
#define NN 2048
#define NE 128
#define NORMC 0.08838834764831845f   // 1/sqrt(128)

// ---- table row layout in d_ws (47 rows x 128 floats, then mflag int) ----
// 0-2  Qc_n  (Wn@wq1)   3 bQ1_n (bn@wq1)   4-5 Qc_d (Wd@wq1)   6 bQ1_d (bd@wq1)
// 7-9  Qn_n  (Wn@wq2)  10 bQ2_n (bn@wq2)  11-12 Qn_d (Wd@wq2) 13 bQ2_d (bd@wq2)
// 14-17 Qs   (Ws@wq3)  18 bQ3  (bs@wq3)
// 19-21 Kc_n (Wn@wk1)  22 bKc_n (bn@wk1)  23-24 Kc_d (Wd@wk1) 25 bKc_d (bd@wk1)
// 26-28 Ak   (Wn@wk2)  29 ck   (bn@wk2)   30-31 Dk  (Wd@wk2)  32 dk   (bd@wk2)
// 33-35 Vc_n (Wn@wv1)  36 bVc_n (bn@wv1)  37-38 Vc_d (Wd@wv1) 39 bVc_d (bd@wv1)
// 40-42 Av   (Wn@wv2)  43 cv   (bn@wv2)   44-45 Dv  (Wd@wv2)  46 dv   (bd@wv2)

__device__ __constant__ int c_lid[47] = {
  0,1,2,3, 4,5,6,          // wq1
  0,1,2,3, 4,5,6,          // wq2
  7,8,9,10,11,             // wq3
  0,1,2,3, 4,5,6,          // wk1
  0,1,2,3, 4,5,6,          // wk2
  0,1,2,3, 4,5,6,          // wv1
  0,1,2,3, 4,5,6           // wv2
};
__device__ __constant__ int c_rid[47] = {
  0,0,0,0,0,0,0,
  1,1,1,1,1,1,1,
  2,2,2,2,2,
  3,3,3,3,3,3,3,
  4,4,4,4,4,4,4,
  5,5,5,5,5,5,5,
  6,6,6,6,6,6,6
};

__global__ __launch_bounds__(128)
void k1_tables(const float* __restrict__ Wn, const float* __restrict__ bn,
               const float* __restrict__ Wd, const float* __restrict__ bd,
               const float* __restrict__ Ws, const float* __restrict__ bs,
               const float* __restrict__ wq, const float* __restrict__ wk,
               const float* __restrict__ wv, const void* __restrict__ maskp,
               float* __restrict__ T)
{
  const int r = blockIdx.x, e = threadIdx.x;
  if (r == 47) {
    // mask element-width detect: bit0 -> 1-byte, bit1 -> 4-byte, none -> 8-byte
    __shared__ int sflag;
    if (e == 0) sflag = 0;
    __syncthreads();
    const unsigned char* mb = (const unsigned char*)maskp;
    int f = 0;
    #pragma unroll
    for (int i = 0; i < 32; ++i) {
      int idx = e * 32 + i;           // scans first 4096 bytes (buffer >= 512 KB)
      unsigned char v = mb[idx];
      if (v) { if (idx & 3) f |= 1; else if (idx & 7) f |= 2; }
    }
    if (f) atomicOr(&sflag, f);
    __syncthreads();
    if (e == 0) ((int*)T)[47 * NE] = sflag;
    return;
  }
  const int li = c_lid[r], ri = c_rid[r];
  const float* lv =
    (li < 3)  ? Wn + li * NE :
    (li == 3) ? bn :
    (li < 6)  ? Wd + (li - 4) * NE :
    (li == 6) ? bd :
    (li < 11) ? Ws + (li - 7) * NE : bs;
  const float* rv =
    (ri == 0) ? wq :
    (ri == 1) ? wq + 128 * NE :
    (ri == 2) ? wq + 256 * NE :
    (ri == 3) ? wk :
    (ri == 4) ? wk + 128 * NE :
    (ri == 5) ? wv : wv + 128 * NE;
  float acc = 0.f;
  #pragma unroll 32
  for (int j = 0; j < 128; ++j) acc += lv[j] * rv[j * NE + e];
  T[r * NE + e] = acc;
}

__global__ __launch_bounds__(1024)
void k2_main(const float* __restrict__ nodef,   // [B,N,3]
             const float* __restrict__ state,   // [B,4]
             const int*   __restrict__ curr_id,
             const int*   __restrict__ next_id,
             const void*  __restrict__ maskp,
             const float* __restrict__ T,       // tables from k1
             float* __restrict__ out)           // [B,128]
{
  const int b = blockIdx.x, t = threadIdx.x;

  __shared__ float qv[NE], kcs[NE];
  __shared__ float scal[8];
  __shared__ float redm[16], redsum[64];
  __shared__ float sse0;

  // ---- uniform scalars (issue early; scalar-unit loads)
  const int mflag = ((const int*)T)[47 * NE];
  const int cid = curr_id[b], nid = next_id[b];
  const float* xcp = nodef + ((size_t)b * NN + cid) * 3;
  const float* xnp = nodef + ((size_t)b * NN + nid) * 3;
  const float xc0 = xcp[0], xc1 = xcp[1], xc2 = xcp[2];
  const float xn0 = xnp[0], xn1 = xnp[1], xn2 = xnp[2];
  const float st0 = state[b*4], st1 = state[b*4+1], st2 = state[b*4+2], st3 = state[b*4+3];
  const float nf00 = nodef[(size_t)b * NN * 3];       // depot coords
  const float nf01 = nodef[(size_t)b * NN * 3 + 1];

  // ---- per-thread node feats (2 nodes), register resident
  const float2* f2 = (const float2*)(nodef + (size_t)b * NN * 3);
  const float2 p0 = f2[3*t], p1 = f2[3*t+1], p2 = f2[3*t+2];
  // node n0=2t feats: p0.x p0.y p1.x ; node n1=2t+1 feats: p1.y p2.x p2.y

  // ---- mask for the 2 nodes
  long long mk0, mk1;
  {
    const size_t off = (size_t)b * NN + 2*t;
    if (mflag & 1)      { const unsigned char* m = (const unsigned char*)maskp; mk0 = m[off]; mk1 = m[off+1]; }
    else if (mflag & 2) { const int* m = (const int*)maskp;                     mk0 = m[off]; mk1 = m[off+1]; }
    else                { const long long* m = (const long long*)maskp;         mk0 = m[off]; mk1 = m[off+1]; }
  }

  // ---- prefetch scal-dot target rows (groups 1-7) before sync
  float tg0 = 0.f, tg1 = 0.f;
  {
    const int gg = t >> 6, l = t & 63;
    if (t < 512 && gg >= 1) {
      const float* vg = (gg == 1) ? T + 29*NE :
                        (gg == 2) ? T + 32*NE :
                        (gg <= 5) ? T + (23 + gg)*NE :   // 26,27,28
                                    T + (24 + gg)*NE;    // 30,31
      tg0 = vg[l]; tg1 = vg[64 + l];
    }
  }

  // ---- t<128: materialize q, kc from tables; prefetch vc + epilogue rows
  float vc_r = 0.f, eav0=0.f, eav1=0.f, eav2=0.f, ecv=0.f, edv0=0.f, edv1=0.f, edv=0.f;
  if (t < NE) {
    const int e = t;
    float q, kc;
    if (cid == 0) {
      q  = xc0*T[ 4*NE+e] + xc1*T[ 5*NE+e] + T[ 6*NE+e];
      kc = xc0*T[23*NE+e] + xc1*T[24*NE+e] + T[25*NE+e];
      vc_r = xc0*T[37*NE+e] + xc1*T[38*NE+e] + T[39*NE+e];
    } else {
      q  = xc0*T[ 0*NE+e] + xc1*T[ 1*NE+e] + xc2*T[ 2*NE+e] + T[ 3*NE+e];
      kc = xc0*T[19*NE+e] + xc1*T[20*NE+e] + xc2*T[21*NE+e] + T[22*NE+e];
      vc_r = xc0*T[33*NE+e] + xc1*T[34*NE+e] + xc2*T[35*NE+e] + T[36*NE+e];
    }
    if (nid == 0) q += xn0*T[11*NE+e] + xn1*T[12*NE+e] + T[13*NE+e];
    else          q += xn0*T[ 7*NE+e] + xn1*T[ 8*NE+e] + xn2*T[ 9*NE+e] + T[10*NE+e];
    q += st0*T[14*NE+e] + st1*T[15*NE+e] + st2*T[16*NE+e] + st3*T[17*NE+e] + T[18*NE+e];
    qv[e] = q; kcs[e] = kc;
    eav0 = T[40*NE+e]; eav1 = T[41*NE+e]; eav2 = T[42*NE+e]; ecv = T[43*NE+e];
    edv0 = T[44*NE+e]; edv1 = T[45*NE+e]; edv  = T[46*NE+e];
  }
  __syncthreads();

  // ---- 8 scalar dots: {q.kc, q.ck, q.dk, Ak@q (3), Dk@q (2)}
  if (t < 512) {
    const int gg = t >> 6, l = t & 63;
    if (gg == 0) { tg0 = kcs[l]; tg1 = kcs[64 + l]; }
    float p = qv[l] * tg0 + qv[64 + l] * tg1;
    #pragma unroll
    for (int o = 32; o; o >>= 1) p += __shfl_down(p, o, 64);
    if (l == 0) scal[gg] = p;
  }
  __syncthreads();

  const float qkc = scal[0], qck = scal[1], qdk = scal[2];
  const float gk0 = scal[3], gk1 = scal[4], gk2 = scal[5];
  const float gdk0 = scal[6], gdk1 = scal[7];

  // ---- compat for 2 register-resident nodes + block max
  float c0, c1;
  if (t == 0) c0 = qkc + qdk + p0.x*gdk0 + p0.y*gdk1;            // node 0 = depot
  else        c0 = qkc + qck + p0.x*gk0 + p0.y*gk1 + p1.x*gk2;
  c1 = qkc + qck + p1.y*gk0 + p2.x*gk1 + p2.y*gk2;
  c0 = mk0 ? c0 * NORMC : -INFINITY;
  c1 = mk1 ? c1 * NORMC : -INFINITY;

  float lmax = fmaxf(c0, c1);
  #pragma unroll
  for (int o = 32; o; o >>= 1) lmax = fmaxf(lmax, __shfl_down(lmax, o, 64));
  if ((t & 63) == 0) redm[t >> 6] = lmax;
  __syncthreads();
  float m = redm[0];
  #pragma unroll
  for (int i = 1; i < 16; ++i) m = fmaxf(m, redm[i]);

  // ---- exp + denom + 3-component weighted feature sums (n>=1)
  const float ex0 = __expf(c0 - m);
  const float ex1 = __expf(c1 - m);
  if (t == 0) sse0 = ex0;
  float le = ex0 + ex1;
  float s0, s1, s2;
  if (t == 0) { s0 = ex1*p1.y; s1 = ex1*p2.x; s2 = ex1*p2.y; }   // exclude depot node
  else {
    s0 = ex0*p0.x + ex1*p1.y;
    s1 = ex0*p0.y + ex1*p2.x;
    s2 = ex0*p1.x + ex1*p2.y;
  }
  #pragma unroll
  for (int o = 32; o; o >>= 1) {
    le += __shfl_down(le, o, 64);
    s0 += __shfl_down(s0, o, 64);
    s1 += __shfl_down(s1, o, 64);
    s2 += __shfl_down(s2, o, 64);
  }
  if ((t & 63) == 0) {
    const int w = t >> 6;
    redsum[w] = le; redsum[16+w] = s0; redsum[32+w] = s1; redsum[48+w] = s2;
  }
  __syncthreads();

  // ---- epilogue on t<128
  if (t < NE) {
    float L = 0, S0 = 0, S1 = 0, S2 = 0;
    #pragma unroll
    for (int i = 0; i < 16; ++i) {
      L += redsum[i]; S0 += redsum[16+i]; S1 += redsum[32+i]; S2 += redsum[48+i];
    }
    const float a0 = sse0 / L;
    const float hv = vc_r
      + (1.0f - a0) * ecv
      + (S0*eav0 + S1*eav1 + S2*eav2) / L
      + a0 * (nf00*edv0 + nf01*edv1 + edv);
    out[(size_t)b * NE + t] = hv;
  }
}

extern "C" void kernel_launch(void* const* d_in, const int* in_sizes, int n_in,
                              void* d_out, int out_size, void* d_ws, size_t ws_size,
                              hipStream_t stream) {
  (void)in_sizes; (void)n_in; (void)out_size; (void)ws_size;
  const float* nodef   = (const float*)d_in[0];
  const float* state   = (const float*)d_in[1];
  const float* W_node  = (const float*)d_in[2];
  const float* b_node  = (const float*)d_in[3];
  const float* W_depot = (const float*)d_in[4];
  const float* b_depot = (const float*)d_in[5];
  const float* W_state = (const float*)d_in[6];
  const float* b_state = (const float*)d_in[7];
  const float* w_q     = (const float*)d_in[8];
  const float* w_k     = (const float*)d_in[9];
  const float* w_v     = (const float*)d_in[10];
  const int*   curr_id = (const int*)d_in[11];
  const int*   next_id = (const int*)d_in[12];
  const void*  maskp   = d_in[13];
  float* T   = (float*)d_ws;
  float* out = (float*)d_out;

  hipLaunchKernelGGL(k1_tables, dim3(48), dim3(128), 0, stream,
                     W_node, b_node, W_depot, b_depot, W_state, b_state,
                     w_q, w_k, w_v, maskp, T);
  hipLaunchKernelGGL(k2_main, dim3(NB), dim3(1024), 0, stream,
                     nodef, state, curr_id, next_id, maskp, T, out);
}